// Round 11
// baseline (370.665 us; speedup 1.0000x reference)
//
#include <hip/hip_runtime.h>
#include <hip/hip_bf16.h>

#define HH 1080
#define WW 1920
#define HWSZ (HH * WW)

typedef __attribute__((ext_vector_type(8))) short bf16x8;
typedef __attribute__((ext_vector_type(4))) float f32x4;
typedef __attribute__((ext_vector_type(4))) short s16x4;

__device__ __forceinline__ float clipf(float x, float lo, float hi) {
    return fminf(fmaxf(x, lo), hi);
}
__device__ __forceinline__ short f2bf(float f) {
    __hip_bfloat16 h = __float2bfloat16(f);
    return *(short*)&h;
}
__device__ __forceinline__ float fpow(float a, float e) {
    return __expf(__logf(a) * e);   // a >= 1e-7 guaranteed by callers
}

// ---------------------------------------------------------------------------
// Kernel 1: classical grade + 3D LUT + blend.
// Writes: xb (planar f32) and xin (NHWC bf16 8ch: x0..2, xb0..2, 0, 0).
// ---------------------------------------------------------------------------
__global__ __launch_bounds__(256) void grade_kernel(
    const float* __restrict__ x, const float* __restrict__ lut,
    const float* __restrict__ cm, const float* __restrict__ cbp,
    const float* __restrict__ shp, const float* __restrict__ mip,
    const float* __restrict__ hip_, const float* __restrict__ cop,
    const float* __restrict__ satp, const float* __restrict__ wap,
    const float* __restrict__ lbp,
    float* __restrict__ xb, __hip_bfloat16* __restrict__ xin)
{
    int i = blockIdx.x * blockDim.x + threadIdx.x;
    if (i >= HWSZ) return;

    float in0 = x[i], in1 = x[HWSZ + i], in2 = x[2 * HWSZ + i];

    float M00 = clipf(cm[0], 0.9f, 1.1f), M01 = clipf(cm[1], 0.9f, 1.1f), M02 = clipf(cm[2], 0.9f, 1.1f);
    float M10 = clipf(cm[3], 0.9f, 1.1f), M11 = clipf(cm[4], 0.9f, 1.1f), M12 = clipf(cm[5], 0.9f, 1.1f);
    float M20 = clipf(cm[6], 0.9f, 1.1f), M21 = clipf(cm[7], 0.9f, 1.1f), M22 = clipf(cm[8], 0.9f, 1.1f);
    float bi0 = clipf(cbp[0], -0.02f, 0.02f);
    float bi1 = clipf(cbp[1], -0.02f, 0.02f);
    float bi2 = clipf(cbp[2], -0.02f, 0.02f);

    float sh  = clipf(shp[0], -0.02f, 0.05f);
    float mi  = clipf(mip[0], 0.95f, 1.05f);
    float hi  = clipf(hip_[0], 0.95f, 1.05f);
    float co  = clipf(cop[0], 0.98f, 1.05f);
    float sat = clipf(satp[0], 0.95f, 1.3f);
    float wa  = clipf(wap[0], -0.02f, 0.05f);
    float lb  = clipf(lbp[0], 0.7f, 0.9f);

    float xc[3];
    xc[0] = M00 * in0 + M01 * in1 + M02 * in2 + bi0;
    xc[1] = M10 * in0 + M11 * in1 + M12 * in2 + bi1;
    xc[2] = M20 * in0 + M21 * in1 + M22 * in2 + bi2;

    float inv_mi = 1.0f / mi, inv_co = 1.0f / co;
    float xg[3];
#pragma unroll
    for (int c = 0; c < 3; c++) {
        float v = xc[c];
        float sm = clipf(1.f - v, 0.f, 1.f);
        sm = sm * sm * sm;
        float xs = v + sh * sm * (1.f - v) * 0.5f;
        float xm = fpow(clipf(xs, 1e-7f, 1.f), inv_mi);
        float hm = clipf(xm, 0.f, 1.f);
        hm = hm * hm * hm;
        float x2 = clipf(xm * (1.f - hm * (1.f - hi) * 0.5f), 0.f, 1.f);
        xg[c] = fpow(clipf(x2, 1e-7f, 1.f), inv_co);
    }

    float luma = 0.299f * xg[0] + 0.587f * xg[1] + 0.114f * xg[2];
    float s0 = luma + sat * (xg[0] - luma);
    float s1 = luma + sat * (xg[1] - luma);
    float s2 = luma + sat * (xg[2] - luma);

    float pr = clipf(s0 * (1.f + wa), 0.f, 1.f);
    float pg = clipf(s1 * (1.f + wa * 0.3f), 0.f, 1.f);
    float pb = clipf(s2 * (1.f - wa * 0.5f), 0.f, 1.f);

    float cr = pr * 32.f, cg = pg * 32.f, cb2 = pb * 32.f;
    float fr = floorf(cr), fgq = floorf(cg), fb = floorf(cb2);
    float fx = cr - fr, fy = cg - fgq, fz = cb2 - fb;
    int x0 = min(max((int)fr, 0), 31);
    int y0 = min(max((int)fgq, 0), 31);
    int z0 = min(max((int)fb, 0), 31);

    const float* base = lut + ((x0 * 33 + y0) * 33 + z0) * 3;
    float pcl[3] = {pr, pg, pb};
    float bl[3];
#pragma unroll
    for (int ch = 0; ch < 3; ch++) {
        float c000 = base[ch];
        float c001 = base[3 + ch];
        float c010 = base[99 + ch];
        float c011 = base[102 + ch];
        float c100 = base[3267 + ch];
        float c101 = base[3270 + ch];
        float c110 = base[3366 + ch];
        float c111 = base[3369 + ch];
        float c00 = c000 * (1.f - fx) + c100 * fx;
        float c01 = c001 * (1.f - fx) + c101 * fx;
        float c10 = c010 * (1.f - fx) + c110 * fx;
        float c11 = c011 * (1.f - fx) + c111 * fx;
        float c0 = c00 * (1.f - fy) + c10 * fy;
        float c1 = c01 * (1.f - fy) + c11 * fy;
        float lv = c0 * (1.f - fz) + c1 * fz;
        bl[ch] = lb * lv + (1.f - lb) * pcl[ch];
        xb[(size_t)ch * HWSZ + i] = bl[ch];
    }

    bf16x8 xi;
    xi[0] = f2bf(in0); xi[1] = f2bf(in1); xi[2] = f2bf(in2);
    xi[3] = f2bf(bl[0]); xi[4] = f2bf(bl[1]); xi[5] = f2bf(bl[2]);
    xi[6] = 0; xi[7] = 0;
    *(bf16x8*)(xin + (size_t)i * 8) = xi;
}

// ---------------------------------------------------------------------------
// Pack kernel: fold BN into weights, emit per-lane MFMA A-fragments + acc-init.
// ---------------------------------------------------------------------------
template <int CI, int CIR, int COUTB, int COUTR, int NG, bool FINAL>
__global__ __launch_bounds__(256) void pack_weights(
    const float* __restrict__ w, const float* __restrict__ w2,
    const float* __restrict__ bg, const float* __restrict__ bb,
    const float* __restrict__ bm, const float* __restrict__ bv,
    short* __restrict__ wp, float* __restrict__ ap)
{
    int t = blockIdx.x * blockDim.x + threadIdx.x;
    constexpr int NFRAG = COUTB * NG * 64;
    if (t < NFRAG) {
        int l    = t & 63;
        int frag = t >> 6;
        int g    = frag % NG;
        int cbk  = frag / NG;
        int mrow = l & 15;
        int sub  = l >> 4;
        int cout = cbk * 16 + mrow;
        float scl = 1.f;
        if (!FINAL)
            scl = (cout < COUTR) ? bg[cout] * rsqrtf(bv[cout] + 1e-5f) : 0.f;
        bf16x8 f;
#pragma unroll
        for (int j = 0; j < 8; j++) {
            int k   = g * 32 + sub * 8 + j;
            int tap = k / CI;
            int ci  = k % CI;
            float val = 0.f;
            if (tap < 9 && ci < CIR && cout < COUTR) {
                if (FINAL)
                    val = (cout < 3) ? w[(cout * CIR + ci) * 9 + tap]
                                     : w2[ci * 9 + tap];
                else
                    val = w[(cout * CIR + ci) * 9 + tap] * scl;
            }
            f[j] = f2bf(val);
        }
        *(bf16x8*)(wp + (size_t)t * 8) = f;
    } else if (t < NFRAG + COUTB * 64) {
        int u   = t - NFRAG;
        int l   = u & 63;
        int cbk = u >> 6;
        int sub = l >> 4;
        f32x4 a;
#pragma unroll
        for (int r = 0; r < 4; r++) {
            int c = cbk * 16 + sub * 4 + r;
            float v = 0.f;
            if (FINAL) {
                v = (c < 3) ? bb[c] : (c == 3 ? bm[0] : 0.f);
            } else if (c < COUTR) {
                float s = bg[c] * rsqrtf(bv[c] + 1e-5f);
                v = bb[c] - bm[c] * s;
            }
            a[r] = v;
        }
        *(f32x4*)(ap + (size_t)u * 4) = a;
    }
}

// ---------------------------------------------------------------------------
// Sliding-window MFMA conv, CI=32 (conv2/conv3), 2 ROWS PER STEP.
// Each wave: one 16-px column tile + one 16-ch output block, marches RPW=8
// rows in 4 double-steps. Window = 4 tap rows (a,b,c,d) x 3 dx = 12 frags.
// Per step: 18 MFMAs as TWO interleaved independent chains (row r uses
// a,b,c; row r+1 uses b,c,d); 6 new loads issued into just-dead tap slots
// mid-step; window advance = register swap (a<->c, b<->d).
// ---------------------------------------------------------------------------
template <int NCB>
__global__ __launch_bounds__(256, 2) void conv_mfma32_slide(
    const __hip_bfloat16* __restrict__ in, int in_y0, int in_rows,
    const short* __restrict__ wp, const float* __restrict__ ap,
    __hip_bfloat16* __restrict__ out, int out_y0, int out_rows)
{
    constexpr int COUT = NCB * 16;     // output channel stride in memory
    constexpr int XT   = 4 / NCB;      // column tiles per block
    constexpr int RPW  = 8;

    int l    = threadIdx.x & 63;
    int wv   = threadIdx.x >> 6;
    int mrow = l & 15;
    int sub  = l >> 4;
    int xt   = wv % XT;
    int chb  = wv / XT;

    int xp = (blockIdx.x * XT + xt) * 16 + mrow;  // this lane's pixel column
    int r0 = blockIdx.y * RPW;                    // strip start (local row)
    if (r0 >= out_rows) return;
    int y0 = out_y0 + r0;

    f32x4 ainit = *(const f32x4*)(ap + ((size_t)chb * 64 + l) * 4);

    bf16x8 wf[9];
#pragma unroll
    for (int g = 0; g < 9; g++)
        wf[g] = *(const bf16x8*)(wp + ((size_t)(chb * 9 + g) * 64 + l) * 8);

    bool xl = xp > 0, xh = xp < WW - 1;
    const __hip_bfloat16* inb = in + sub * 8;

#define ROWLOAD(yy, d0, d1, d2)                                              \
    do {                                                                     \
        int ybuf_ = min(max((yy) - in_y0, 0), in_rows - 1);                  \
        const __hip_bfloat16* rb_ = inb + (size_t)ybuf_ * (WW * 32);         \
        bool yok_ = (unsigned)(yy) < (unsigned)HH;                           \
        bf16x8 z_ = {0, 0, 0, 0, 0, 0, 0, 0};                                \
        d0 = (yok_ && xl) ? *(const bf16x8*)(rb_ + (size_t)(xp - 1) * 32) : z_; \
        d1 = yok_         ? *(const bf16x8*)(rb_ + (size_t)xp * 32)       : z_; \
        d2 = (yok_ && xh) ? *(const bf16x8*)(rb_ + (size_t)(xp + 1) * 32) : z_; \
    } while (0)

#define MFMA(w_, t_, acc_) \
    acc_ = __builtin_amdgcn_mfma_f32_16x16x32_bf16(w_, t_, acc_, 0, 0, 0)

    // Window rows: a = r-1, b = r, c = r+1, d = r+2
    bf16x8 a0, a1, a2, b0, b1, b2, c0, c1, c2, d0, d1, d2;
    ROWLOAD(y0 - 1, a0, a1, a2);
    ROWLOAD(y0,     b0, b1, b2);
    ROWLOAD(y0 + 1, c0, c1, c2);
    ROWLOAD(y0 + 2, d0, d1, d2);

#pragma unroll
    for (int s = 0; s < RPW / 2; s++) {
        int r = r0 + 2 * s;
        f32x4 accA = ainit;   // output row r     (taps a,b,c)
        f32x4 accB = ainit;   // output row r + 1 (taps b,c,d)

        MFMA(wf[0], a0, accA);  MFMA(wf[0], b0, accB);
        MFMA(wf[1], a1, accA);  MFMA(wf[1], b1, accB);
        MFMA(wf[2], a2, accA);  MFMA(wf[2], b2, accB);
        // a dead -> load row r+3 into a-slots (flies under next 12 MFMAs)
        if (s < RPW / 2 - 1) ROWLOAD(y0 + 2 * s + 3, a0, a1, a2);
        MFMA(wf[3], b0, accA);  MFMA(wf[3], c0, accB);
        MFMA(wf[4], b1, accA);  MFMA(wf[4], c1, accB);
        MFMA(wf[5], b2, accA);  MFMA(wf[5], c2, accB);
        // b dead -> load row r+4 into b-slots
        if (s < RPW / 2 - 1) ROWLOAD(y0 + 2 * s + 4, b0, b1, b2);
        MFMA(wf[6], c0, accA);  MFMA(wf[6], d0, accB);
        MFMA(wf[7], c1, accA);  MFMA(wf[7], d1, accB);
        MFMA(wf[8], c2, accA);  MFMA(wf[8], d2, accB);

        if (r < out_rows) {
            s16x4 s_;
#pragma unroll
            for (int q = 0; q < 4; q++) s_[q] = f2bf(fmaxf(accA[q], 0.f));
            *(s16x4*)(out + ((size_t)r * WW + xp) * COUT + chb * 16 + sub * 4) = s_;
        }
        if (r + 1 < out_rows) {
            s16x4 s_;
#pragma unroll
            for (int q = 0; q < 4; q++) s_[q] = f2bf(fmaxf(accB[q], 0.f));
            *(s16x4*)(out + ((size_t)(r + 1) * WW + xp) * COUT + chb * 16 + sub * 4) = s_;
        }

        // Advance window 2 rows: swap a<->c (a-slots hold r+3), b<->d
        // (b-slots hold r+4). Pure renaming under full unroll.
        {
            bf16x8 t;
            t = a0; a0 = c0; c0 = t;
            t = a1; a1 = c1; c1 = t;
            t = a2; a2 = c2; c2 = t;
            t = b0; b0 = d0; d0 = t;
            t = b1; b1 = d1; d1 = t;
            t = b2; b2 = d2; d2 = t;
        }
    }
#undef MFMA
#undef ROWLOAD
}

// ---------------------------------------------------------------------------
// Tile-pipelined MFMA conv (conv1 CI=8 and FINAL CI=16).
// FINAL epilogue is wave-parallel (one transcendental per lane).
// ---------------------------------------------------------------------------
template <int CI, int COUTB, int NG, bool FINAL>
__global__ __launch_bounds__(256, 2) void conv_mfma(
    const __hip_bfloat16* __restrict__ in, int in_y0, int in_rows,
    const short* __restrict__ wp, const float* __restrict__ ap,
    __hip_bfloat16* __restrict__ out, int out_y0, int out_rows,
    const float* __restrict__ xb, const float* __restrict__ stp,
    float* __restrict__ fout)
{
    constexpr int COUT = COUTB * 16;
    constexpr int SEGW = 192;
    constexpr int NT   = SEGW / 16;   // 12, even

    int l    = threadIdx.x & 63;
    int wv   = threadIdx.x >> 6;
    int lrow = blockIdx.y * 4 + wv;
    if (lrow >= out_rows) return;
    int y    = out_y0 + lrow;
    int x0   = blockIdx.x * SEGW;
    int mrow = l & 15;
    int sub  = l >> 4;

    f32x4 ainit[COUTB];
#pragma unroll
    for (int cbk = 0; cbk < COUTB; cbk++)
        ainit[cbk] = *(const f32x4*)(ap + ((size_t)cbk * 64 + l) * 4);

    bf16x8 wf[COUTB][NG];
#pragma unroll
    for (int cbk = 0; cbk < COUTB; cbk++)
#pragma unroll
        for (int g = 0; g < NG; g++)
            wf[cbk][g] = *(const bf16x8*)(wp + ((size_t)(cbk * NG + g) * 64 + l) * 8);

    float stv = 0.f;
    if (FINAL) stv = clipf(stp[0], 0.02f, 0.2f);

    const __hip_bfloat16* baseg[NG];
    int dxg[NG];
    bool okg[NG];
#pragma unroll
    for (int g = 0; g < NG; g++) {
        int kl  = g * 32 + sub * 8;
        int tap = kl / CI;
        int cib = kl % CI;
        int dy = (tap < 9) ? tap / 3 - 1 : 0;
        int dx = (tap < 9) ? tap % 3 - 1 : 0;
        int yy = y + dy;
        okg[g] = (yy >= 0 && yy < HH);
        baseg[g] = in + ((long)(yy - in_y0) * WW + dx) * CI + cib;
        dxg[g] = dx;
    }

#define LOADB(t, buf)                                                        \
    do {                                                                     \
        int xp_ = x0 + (t) * 16 + mrow;                                      \
        _Pragma("unroll")                                                    \
        for (int g = 0; g < NG; g++) {                                       \
            int xx_ = xp_ + dxg[g];                                          \
            bf16x8 v_ = {0, 0, 0, 0, 0, 0, 0, 0};                            \
            if (okg[g] && (unsigned)xx_ < (unsigned)WW)                      \
                v_ = *(const bf16x8*)(baseg[g] + (size_t)xp_ * CI);          \
            buf[g] = v_;                                                     \
        }                                                                    \
    } while (0)

#define COMPUTE(t, buf)                                                      \
    do {                                                                     \
        int xp_ = x0 + (t) * 16 + mrow;                                      \
        float xbv_ = 0.f;                                                    \
        if (FINAL && sub < 3)                                                \
            xbv_ = xb[(size_t)sub * HWSZ + (size_t)y * WW + xp_];            \
        f32x4 acc[COUTB];                                                    \
        _Pragma("unroll")                                                    \
        for (int cbk = 0; cbk < COUTB; cbk++) acc[cbk] = ainit[cbk];         \
        _Pragma("unroll")                                                    \
        for (int g = 0; g < NG; g++) {                                       \
            _Pragma("unroll")                                                \
            for (int cbk = 0; cbk < COUTB; cbk++)                            \
                acc[cbk] = __builtin_amdgcn_mfma_f32_16x16x32_bf16(          \
                    wf[cbk][g], buf[g], acc[cbk], 0, 0, 0);                  \
        }                                                                    \
        if constexpr (!FINAL) {                                              \
            _Pragma("unroll")                                                \
            for (int cbk = 0; cbk < COUTB; cbk++) {                          \
                s16x4 s_;                                                    \
                _Pragma("unroll")                                            \
                for (int q = 0; q < 4; q++)                                  \
                    s_[q] = f2bf(fmaxf(acc[cbk][q], 0.f));                   \
                *(s16x4*)(out + ((size_t)lrow * WW + xp_) * COUT +           \
                          cbk * 16 + sub * 4) = s_;                          \
            }                                                                \
        } else {                                                             \
            float bc0_ = __shfl(acc[0][0], mrow);                            \
            float bc1_ = __shfl(acc[0][1], mrow);                            \
            float bc2_ = __shfl(acc[0][2], mrow);                            \
            float bc3_ = __shfl(acc[0][3], mrow);                            \
            float mv_ = (sub == 0) ? bc0_ : (sub == 1) ? bc1_                \
                      : (sub == 2) ? bc2_ : bc3_;                            \
            float e_  = __expf((sub == 3) ? -mv_ : 2.f * mv_);               \
            float tv_ = (sub == 3) ? 1.f / (1.f + e_)                        \
                                   : 1.f - 2.f / (1.f + e_);                 \
            float atv_ = __shfl(tv_, 48 + mrow);                             \
            if (sub < 3) {                                                   \
                size_t off_ = (size_t)sub * HWSZ + (size_t)y * WW + xp_;     \
                fout[off_] = clipf(xbv_ + stv * tv_ * atv_, 0.f, 1.f);       \
            }                                                                \
        }                                                                    \
    } while (0)

    bf16x8 bufA[NG], bufB[NG];
    LOADB(0, bufA);
#pragma unroll
    for (int tt = 0; tt < NT; tt += 2) {
        LOADB(tt + 1, bufB);
        COMPUTE(tt, bufA);
        if (tt + 2 < NT) LOADB(tt + 2, bufA);
        COMPUTE(tt + 1, bufB);
    }
#undef LOADB
#undef COMPUTE
}

// ---------------------------------------------------------------------------
extern "C" void kernel_launch(void* const* d_in, const int* in_sizes, int n_in,
                              void* d_out, int out_size, void* d_ws, size_t ws_size,
                              hipStream_t stream)
{
    const float* x   = (const float*)d_in[0];
    const float* lut = (const float*)d_in[1];
    const float* cm  = (const float*)d_in[2];
    const float* cb  = (const float*)d_in[3];
    const float* sh  = (const float*)d_in[4];
    const float* mi  = (const float*)d_in[5];
    const float* hi  = (const float*)d_in[6];
    const float* co  = (const float*)d_in[7];
    const float* sa  = (const float*)d_in[8];
    const float* wa  = (const float*)d_in[9];
    const float* lb  = (const float*)d_in[10];
    const float* st  = (const float*)d_in[11];
    const float* w1  = (const float*)d_in[12];
    const float* g1  = (const float*)d_in[13];
    const float* b1  = (const float*)d_in[14];
    const float* m1  = (const float*)d_in[15];
    const float* v1  = (const float*)d_in[16];
    const float* w2  = (const float*)d_in[17];
    const float* g2  = (const float*)d_in[18];
    const float* b2  = (const float*)d_in[19];
    const float* m2  = (const float*)d_in[20];
    const float* v2  = (const float*)d_in[21];
    const float* w3  = (const float*)d_in[22];
    const float* g3  = (const float*)d_in[23];
    const float* b3  = (const float*)d_in[24];
    const float* m3  = (const float*)d_in[25];
    const float* v3  = (const float*)d_in[26];
    const float* rw  = (const float*)d_in[27];
    const float* rb  = (const float*)d_in[28];
    const float* aw  = (const float*)d_in[29];
    const float* ab  = (const float*)d_in[30];

    // Workspace: xb f32 24.9MB | xin bf16 33.2MB | f1 66.7MB | f2 66.7MB | packs ~46KB
    char* ws = (char*)d_ws;
    const size_t XB_BYTES  = (size_t)3 * HWSZ * sizeof(float);
    const size_t XIN_BYTES = (size_t)8 * HWSZ * sizeof(__hip_bfloat16);
    const size_t F_BYTES   = (size_t)32 * 543 * WW * sizeof(__hip_bfloat16);
    float* xb = (float*)ws;
    __hip_bfloat16* xin = (__hip_bfloat16*)(ws + XB_BYTES);
    __hip_bfloat16* f1  = (__hip_bfloat16*)(ws + XB_BYTES + XIN_BYTES);
    __hip_bfloat16* f2  = (__hip_bfloat16*)(ws + XB_BYTES + XIN_BYTES + F_BYTES);
    __hip_bfloat16* f3  = f1;   // f1 dead once conv2 of this half is done

    char* pk = ws + XB_BYTES + XIN_BYTES + 2 * F_BYTES;
    short* wp1 = (short*)(pk);               // 6144 B
    float* ap1 = (float*)(pk + 6144);        // 2048 B
    short* wp2 = (short*)(pk + 8192);        // 18432 B
    float* ap2 = (float*)(pk + 26624);       // 2048 B
    short* wp3 = (short*)(pk + 28672);       // 9216 B
    float* ap3 = (float*)(pk + 37888);       // 1024 B
    short* wp4 = (short*)(pk + 38912);       // 5120 B
    float* ap4 = (float*)(pk + 44032);       // 1024 B

    pack_weights<8, 6, 2, 32, 3, false><<<2, 256, 0, stream>>>(
        w1, nullptr, g1, b1, m1, v1, wp1, ap1);
    pack_weights<32, 32, 2, 32, 9, false><<<5, 256, 0, stream>>>(
        w2, nullptr, g2, b2, m2, v2, wp2, ap2);
    pack_weights<32, 32, 1, 16, 9, false><<<3, 256, 0, stream>>>(
        w3, nullptr, g3, b3, m3, v3, wp3, ap3);
    pack_weights<16, 16, 1, 4, 5, true><<<2, 256, 0, stream>>>(
        rw, aw, rb, rb, ab, ab, wp4, ap4);

    {
        int grid = (HWSZ + 255) / 256;
        grade_kernel<<<grid, 256, 0, stream>>>(x, lut, cm, cb, sh, mi, hi, co,
                                               sa, wa, lb, xb, xin);
    }

    for (int h = 0; h < 2; h++) {
        int r0 = (h == 0) ? 0 : HH / 2;
        int r1 = (h == 0) ? HH / 2 : HH;

        int f1_y0 = max(r0 - 3, 0), f1_y1 = min(r1 + 3, HH);
        int f2_y0 = max(r0 - 2, 0), f2_y1 = min(r1 + 2, HH);
        int f3_y0 = max(r0 - 1, 0), f3_y1 = min(r1 + 1, HH);
        int f1_rows = f1_y1 - f1_y0;
        int f2_rows = f2_y1 - f2_y0;
        int f3_rows = f3_y1 - f3_y0;
        int out_rows = r1 - r0;

        dim3 blk(256);
        dim3 gr1(10, (f1_rows + 3) / 4);
        dim3 gr2s(60, (f2_rows + 7) / 8);   // NCB=2: XT=2, 32 px/block
        dim3 gr3s(30, (f3_rows + 7) / 8);   // NCB=1: XT=4, 64 px/block
        dim3 gr4(10, (out_rows + 3) / 4);

        // conv1: 6(->8 padded) -> 32, K=96 (12 taps, 3 zero)
        conv_mfma<8, 2, 3, false><<<gr1, blk, 0, stream>>>(
            xin, 0, HH, wp1, ap1, f1, f1_y0, f1_rows,
            nullptr, nullptr, nullptr);
        // conv2: 32 -> 32 (2-row dual-chain slide, channel-split waves)
        conv_mfma32_slide<2><<<gr2s, blk, 0, stream>>>(
            f1, f1_y0, f1_rows, wp2, ap2, f2, f2_y0, f2_rows);
        // conv3: 32 -> 16 (2-row dual-chain slide)
        conv_mfma32_slide<1><<<gr3s, blk, 0, stream>>>(
            f2, f2_y0, f2_rows, wp3, ap3, f3, f3_y0, f3_rows);
        // final: 16 -> 4 (res0-2 + attn), K=160, fused blend + wave-parallel
        // epilogue
        conv_mfma<16, 1, 5, true><<<gr4, blk, 0, stream>>>(
            f3, f3_y0, f3_rows, wp4, ap4, nullptr, r0, out_rows,
            xb, st, (float*)d_out);
    }
}

// Round 13
// 342.200 us; speedup vs baseline: 1.0832x; 1.0832x over previous
//
#include <hip/hip_runtime.h>
#include <hip/hip_bf16.h>

#define HH 1080
#define WW 1920
#define HWSZ (HH * WW)

typedef __attribute__((ext_vector_type(8))) short bf16x8;
typedef __attribute__((ext_vector_type(4))) float f32x4;
typedef __attribute__((ext_vector_type(4))) short s16x4;
typedef __attribute__((ext_vector_type(8))) unsigned char u8x8;

__device__ __forceinline__ float clipf(float x, float lo, float hi) {
    return fminf(fmaxf(x, lo), hi);
}
__device__ __forceinline__ short f2bf(float f) {
    __hip_bfloat16 h = __float2bfloat16(f);
    return *(short*)&h;
}
// f32 -> OCP e4m3 fp8 via native cvt (no hip_fp8.h dependency)
__device__ __forceinline__ unsigned char f2fp8(float f) {
    int p = __builtin_amdgcn_cvt_pk_fp8_f32(f, 0.f, 0, false);
    return (unsigned char)(p & 0xFF);
}
__device__ __forceinline__ unsigned int pack4_fp8(float a, float b, float c, float d) {
    int p = __builtin_amdgcn_cvt_pk_fp8_f32(a, b, 0, false);
    p = __builtin_amdgcn_cvt_pk_fp8_f32(c, d, p, true);
    return (unsigned int)p;
}
__device__ __forceinline__ float fpow(float a, float e) {
    return __expf(__logf(a) * e);   // a >= 1e-7 guaranteed by callers
}

// ---------------------------------------------------------------------------
// Kernel 1: classical grade + 3D LUT + blend.
// Writes: xb (planar f32) and xin (NHWC bf16 8ch: x0..2, xb0..2, 0, 0).
// ---------------------------------------------------------------------------
__global__ __launch_bounds__(256) void grade_kernel(
    const float* __restrict__ x, const float* __restrict__ lut,
    const float* __restrict__ cm, const float* __restrict__ cbp,
    const float* __restrict__ shp, const float* __restrict__ mip,
    const float* __restrict__ hip_, const float* __restrict__ cop,
    const float* __restrict__ satp, const float* __restrict__ wap,
    const float* __restrict__ lbp,
    float* __restrict__ xb, __hip_bfloat16* __restrict__ xin)
{
    int i = blockIdx.x * blockDim.x + threadIdx.x;
    if (i >= HWSZ) return;

    float in0 = x[i], in1 = x[HWSZ + i], in2 = x[2 * HWSZ + i];

    float M00 = clipf(cm[0], 0.9f, 1.1f), M01 = clipf(cm[1], 0.9f, 1.1f), M02 = clipf(cm[2], 0.9f, 1.1f);
    float M10 = clipf(cm[3], 0.9f, 1.1f), M11 = clipf(cm[4], 0.9f, 1.1f), M12 = clipf(cm[5], 0.9f, 1.1f);
    float M20 = clipf(cm[6], 0.9f, 1.1f), M21 = clipf(cm[7], 0.9f, 1.1f), M22 = clipf(cm[8], 0.9f, 1.1f);
    float bi0 = clipf(cbp[0], -0.02f, 0.02f);
    float bi1 = clipf(cbp[1], -0.02f, 0.02f);
    float bi2 = clipf(cbp[2], -0.02f, 0.02f);

    float sh  = clipf(shp[0], -0.02f, 0.05f);
    float mi  = clipf(mip[0], 0.95f, 1.05f);
    float hi  = clipf(hip_[0], 0.95f, 1.05f);
    float co  = clipf(cop[0], 0.98f, 1.05f);
    float sat = clipf(satp[0], 0.95f, 1.3f);
    float wa  = clipf(wap[0], -0.02f, 0.05f);
    float lb  = clipf(lbp[0], 0.7f, 0.9f);

    float xc[3];
    xc[0] = M00 * in0 + M01 * in1 + M02 * in2 + bi0;
    xc[1] = M10 * in0 + M11 * in1 + M12 * in2 + bi1;
    xc[2] = M20 * in0 + M21 * in1 + M22 * in2 + bi2;

    float inv_mi = 1.0f / mi, inv_co = 1.0f / co;
    float xg[3];
#pragma unroll
    for (int c = 0; c < 3; c++) {
        float v = xc[c];
        float sm = clipf(1.f - v, 0.f, 1.f);
        sm = sm * sm * sm;
        float xs = v + sh * sm * (1.f - v) * 0.5f;
        float xm = fpow(clipf(xs, 1e-7f, 1.f), inv_mi);
        float hm = clipf(xm, 0.f, 1.f);
        hm = hm * hm * hm;
        float x2 = clipf(xm * (1.f - hm * (1.f - hi) * 0.5f), 0.f, 1.f);
        xg[c] = fpow(clipf(x2, 1e-7f, 1.f), inv_co);
    }

    float luma = 0.299f * xg[0] + 0.587f * xg[1] + 0.114f * xg[2];
    float s0 = luma + sat * (xg[0] - luma);
    float s1 = luma + sat * (xg[1] - luma);
    float s2 = luma + sat * (xg[2] - luma);

    float pr = clipf(s0 * (1.f + wa), 0.f, 1.f);
    float pg = clipf(s1 * (1.f + wa * 0.3f), 0.f, 1.f);
    float pb = clipf(s2 * (1.f - wa * 0.5f), 0.f, 1.f);

    float cr = pr * 32.f, cg = pg * 32.f, cb2 = pb * 32.f;
    float fr = floorf(cr), fgq = floorf(cg), fb = floorf(cb2);
    float fx = cr - fr, fy = cg - fgq, fz = cb2 - fb;
    int x0 = min(max((int)fr, 0), 31);
    int y0 = min(max((int)fgq, 0), 31);
    int z0 = min(max((int)fb, 0), 31);

    const float* base = lut + ((x0 * 33 + y0) * 33 + z0) * 3;
    float pcl[3] = {pr, pg, pb};
    float bl[3];
#pragma unroll
    for (int ch = 0; ch < 3; ch++) {
        float c000 = base[ch];
        float c001 = base[3 + ch];
        float c010 = base[99 + ch];
        float c011 = base[102 + ch];
        float c100 = base[3267 + ch];
        float c101 = base[3270 + ch];
        float c110 = base[3366 + ch];
        float c111 = base[3369 + ch];
        float c00 = c000 * (1.f - fx) + c100 * fx;
        float c01 = c001 * (1.f - fx) + c101 * fx;
        float c10 = c010 * (1.f - fx) + c110 * fx;
        float c11 = c011 * (1.f - fx) + c111 * fx;
        float c0 = c00 * (1.f - fy) + c10 * fy;
        float c1 = c01 * (1.f - fy) + c11 * fy;
        float lv = c0 * (1.f - fz) + c1 * fz;
        bl[ch] = lb * lv + (1.f - lb) * pcl[ch];
        xb[(size_t)ch * HWSZ + i] = bl[ch];
    }

    bf16x8 xi;
    xi[0] = f2bf(in0); xi[1] = f2bf(in1); xi[2] = f2bf(in2);
    xi[3] = f2bf(bl[0]); xi[4] = f2bf(bl[1]); xi[5] = f2bf(bl[2]);
    xi[6] = 0; xi[7] = 0;
    *(bf16x8*)(xin + (size_t)i * 8) = xi;
}

// ---------------------------------------------------------------------------
// Pack kernel: fold BN into weights, emit per-lane MFMA A-fragments + acc-init.
// FP8W=false: bf16 frags at wp + t*16 B.  FP8W=true: fp8 frags at wp + t*8 B.
// ---------------------------------------------------------------------------
template <int CI, int CIR, int COUTB, int COUTR, int NG, bool FINAL, bool FP8W>
__global__ __launch_bounds__(256) void pack_weights(
    const float* __restrict__ w, const float* __restrict__ w2,
    const float* __restrict__ bg, const float* __restrict__ bb,
    const float* __restrict__ bm, const float* __restrict__ bv,
    unsigned char* __restrict__ wp, float* __restrict__ ap)
{
    int t = blockIdx.x * blockDim.x + threadIdx.x;
    constexpr int NFRAG = COUTB * NG * 64;
    if (t < NFRAG) {
        int l    = t & 63;
        int frag = t >> 6;
        int g    = frag % NG;
        int cbk  = frag / NG;
        int mrow = l & 15;
        int sub  = l >> 4;
        int cout = cbk * 16 + mrow;
        float scl = 1.f;
        if (!FINAL)
            scl = (cout < COUTR) ? bg[cout] * rsqrtf(bv[cout] + 1e-5f) : 0.f;
        float vals[8];
#pragma unroll
        for (int j = 0; j < 8; j++) {
            int k   = g * 32 + sub * 8 + j;
            int tap = k / CI;
            int ci  = k % CI;
            float val = 0.f;
            if (tap < 9 && ci < CIR && cout < COUTR) {
                if (FINAL)
                    val = (cout < 3) ? w[(cout * CIR + ci) * 9 + tap]
                                     : w2[ci * 9 + tap];
                else
                    val = w[(cout * CIR + ci) * 9 + tap] * scl;
            }
            vals[j] = val;
        }
        if constexpr (FP8W) {
            unsigned int lo = pack4_fp8(vals[0], vals[1], vals[2], vals[3]);
            unsigned int hi = pack4_fp8(vals[4], vals[5], vals[6], vals[7]);
            unsigned int p[2] = {lo, hi};
            *(u8x8*)(wp + (size_t)t * 8) = *(u8x8*)p;
        } else {
            bf16x8 f;
#pragma unroll
            for (int j = 0; j < 8; j++) f[j] = f2bf(vals[j]);
            *(bf16x8*)(wp + (size_t)t * 16) = f;
        }
    } else if (t < NFRAG + COUTB * 64) {
        int u   = t - NFRAG;
        int l   = u & 63;
        int cbk = u >> 6;
        int sub = l >> 4;
        f32x4 a;
#pragma unroll
        for (int r = 0; r < 4; r++) {
            int c = cbk * 16 + sub * 4 + r;
            float v = 0.f;
            if (FINAL) {
                v = (c < 3) ? bb[c] : (c == 3 ? bm[0] : 0.f);
            } else if (c < COUTR) {
                float s = bg[c] * rsqrtf(bv[c] + 1e-5f);
                v = bb[c] - bm[c] * s;
            }
            a[r] = v;
        }
        *(f32x4*)(ap + (size_t)u * 4) = a;
    }
}

// ---------------------------------------------------------------------------
// Sliding-window fp8 MFMA conv, CI=32 (conv2/conv3), 2 rows per step.
// Input/weights fp8 e4m3 (8 B/lane fragments); output fp8. 4-row tap window,
// two interleaved MFMA chains, loads into dead slots mid-step.
// ---------------------------------------------------------------------------
template <int NCB>
__global__ __launch_bounds__(256, 4) void conv_fp8_slide(
    const unsigned char* __restrict__ in, int in_y0, int in_rows,
    const unsigned char* __restrict__ wp, const float* __restrict__ ap,
    unsigned char* __restrict__ out, int out_y0, int out_rows)
{
    constexpr int COUT = NCB * 16;     // output channel stride (bytes)
    constexpr int XT   = 4 / NCB;      // column tiles per block
    constexpr int RPW  = 8;

    int l    = threadIdx.x & 63;
    int wv   = threadIdx.x >> 6;
    int mrow = l & 15;
    int sub  = l >> 4;
    int xt   = wv % XT;
    int chb  = wv / XT;

    int xp = (blockIdx.x * XT + xt) * 16 + mrow;
    int r0 = blockIdx.y * RPW;
    if (r0 >= out_rows) return;
    int y0 = out_y0 + r0;

    f32x4 ainit = *(const f32x4*)(ap + ((size_t)chb * 64 + l) * 4);

    u8x8 wf[9];
#pragma unroll
    for (int g = 0; g < 9; g++)
        wf[g] = *(const u8x8*)(wp + ((size_t)(chb * 9 + g) * 64 + l) * 8);

    bool xl = xp > 0, xh = xp < WW - 1;
    const unsigned char* inb = in + sub * 8;

#define ROWLOAD(yy, d0, d1, d2)                                              \
    do {                                                                     \
        int ybuf_ = min(max((yy) - in_y0, 0), in_rows - 1);                  \
        const unsigned char* rb_ = inb + (size_t)ybuf_ * (WW * 32);          \
        bool yok_ = (unsigned)(yy) < (unsigned)HH;                           \
        u8x8 z_ = {0, 0, 0, 0, 0, 0, 0, 0};                                  \
        d0 = (yok_ && xl) ? *(const u8x8*)(rb_ + (size_t)(xp - 1) * 32) : z_; \
        d1 = yok_         ? *(const u8x8*)(rb_ + (size_t)xp * 32)       : z_; \
        d2 = (yok_ && xh) ? *(const u8x8*)(rb_ + (size_t)(xp + 1) * 32) : z_; \
    } while (0)

#define MFMA(w_, t_, acc_)                                                   \
    acc_ = __builtin_amdgcn_mfma_f32_16x16x32_fp8_fp8(                       \
        *(const long long*)&(w_), *(const long long*)&(t_), acc_, 0, 0, 0)

    u8x8 a0, a1, a2, b0, b1, b2, c0, c1, c2, d0, d1, d2;
    ROWLOAD(y0 - 1, a0, a1, a2);
    ROWLOAD(y0,     b0, b1, b2);
    ROWLOAD(y0 + 1, c0, c1, c2);
    ROWLOAD(y0 + 2, d0, d1, d2);

#pragma unroll
    for (int s = 0; s < RPW / 2; s++) {
        int r = r0 + 2 * s;
        f32x4 accA = ainit;   // row r     (taps a,b,c)
        f32x4 accB = ainit;   // row r + 1 (taps b,c,d)

        MFMA(wf[0], a0, accA);  MFMA(wf[0], b0, accB);
        MFMA(wf[1], a1, accA);  MFMA(wf[1], b1, accB);
        MFMA(wf[2], a2, accA);  MFMA(wf[2], b2, accB);
        if (s < RPW / 2 - 1) ROWLOAD(y0 + 2 * s + 3, a0, a1, a2);
        MFMA(wf[3], b0, accA);  MFMA(wf[3], c0, accB);
        MFMA(wf[4], b1, accA);  MFMA(wf[4], c1, accB);
        MFMA(wf[5], b2, accA);  MFMA(wf[5], c2, accB);
        if (s < RPW / 2 - 1) ROWLOAD(y0 + 2 * s + 4, b0, b1, b2);
        MFMA(wf[6], c0, accA);  MFMA(wf[6], d0, accB);
        MFMA(wf[7], c1, accA);  MFMA(wf[7], d1, accB);
        MFMA(wf[8], c2, accA);  MFMA(wf[8], d2, accB);

        if (r < out_rows) {
            unsigned int p = pack4_fp8(fmaxf(accA[0], 0.f), fmaxf(accA[1], 0.f),
                                       fmaxf(accA[2], 0.f), fmaxf(accA[3], 0.f));
            *(unsigned int*)(out + ((size_t)r * WW + xp) * COUT + chb * 16 + sub * 4) = p;
        }
        if (r + 1 < out_rows) {
            unsigned int p = pack4_fp8(fmaxf(accB[0], 0.f), fmaxf(accB[1], 0.f),
                                       fmaxf(accB[2], 0.f), fmaxf(accB[3], 0.f));
            *(unsigned int*)(out + ((size_t)(r + 1) * WW + xp) * COUT + chb * 16 + sub * 4) = p;
        }

        {
            u8x8 t;
            t = a0; a0 = c0; c0 = t;
            t = a1; a1 = c1; c1 = t;
            t = a2; a2 = c2; c2 = t;
            t = b0; b0 = d0; d0 = t;
            t = b1; b1 = d1; d1 = t;
            t = b2; b2 = d2; d2 = t;
        }
    }
#undef MFMA
#undef ROWLOAD
}

// ---------------------------------------------------------------------------
// conv1: bf16 input (xin NHWC 8ch) + bf16 weights -> fp8 output. Tile-
// pipelined as before.
// ---------------------------------------------------------------------------
__global__ __launch_bounds__(256, 2) void conv1_kernel(
    const __hip_bfloat16* __restrict__ in,
    const unsigned char* __restrict__ wp, const float* __restrict__ ap,
    unsigned char* __restrict__ out, int out_y0, int out_rows)
{
    constexpr int CI = 8, COUTB = 2, NG = 3, COUT = 32;
    constexpr int SEGW = 192;
    constexpr int NT   = SEGW / 16;

    int l    = threadIdx.x & 63;
    int wv   = threadIdx.x >> 6;
    int lrow = blockIdx.y * 4 + wv;
    if (lrow >= out_rows) return;
    int y    = out_y0 + lrow;
    int x0   = blockIdx.x * SEGW;
    int mrow = l & 15;
    int sub  = l >> 4;

    f32x4 ainit[COUTB];
#pragma unroll
    for (int cbk = 0; cbk < COUTB; cbk++)
        ainit[cbk] = *(const f32x4*)(ap + ((size_t)cbk * 64 + l) * 4);

    bf16x8 wf[COUTB][NG];
#pragma unroll
    for (int cbk = 0; cbk < COUTB; cbk++)
#pragma unroll
        for (int g = 0; g < NG; g++)
            wf[cbk][g] = *(const bf16x8*)((const short*)wp +
                ((size_t)(cbk * NG + g) * 64 + l) * 8);

    const __hip_bfloat16* baseg[NG];
    int dxg[NG];
    bool okg[NG];
#pragma unroll
    for (int g = 0; g < NG; g++) {
        int kl  = g * 32 + sub * 8;
        int tap = kl / CI;
        int cib = kl % CI;
        int dy = (tap < 9) ? tap / 3 - 1 : 0;
        int dx = (tap < 9) ? tap % 3 - 1 : 0;
        int yy = y + dy;
        okg[g] = (yy >= 0 && yy < HH);
        baseg[g] = in + ((long)yy * WW + dx) * CI + cib;
        dxg[g] = dx;
    }

#define LOADB(t, buf)                                                        \
    do {                                                                     \
        int xp_ = x0 + (t) * 16 + mrow;                                      \
        _Pragma("unroll")                                                    \
        for (int g = 0; g < NG; g++) {                                       \
            int xx_ = xp_ + dxg[g];                                          \
            bf16x8 v_ = {0, 0, 0, 0, 0, 0, 0, 0};                            \
            if (okg[g] && (unsigned)xx_ < (unsigned)WW)                      \
                v_ = *(const bf16x8*)(baseg[g] + (size_t)xp_ * CI);          \
            buf[g] = v_;                                                     \
        }                                                                    \
    } while (0)

#define COMPUTE(t, buf)                                                      \
    do {                                                                     \
        int xp_ = x0 + (t) * 16 + mrow;                                      \
        f32x4 acc[COUTB];                                                    \
        _Pragma("unroll")                                                    \
        for (int cbk = 0; cbk < COUTB; cbk++) acc[cbk] = ainit[cbk];         \
        _Pragma("unroll")                                                    \
        for (int g = 0; g < NG; g++) {                                       \
            _Pragma("unroll")                                                \
            for (int cbk = 0; cbk < COUTB; cbk++)                            \
                acc[cbk] = __builtin_amdgcn_mfma_f32_16x16x32_bf16(          \
                    wf[cbk][g], buf[g], acc[cbk], 0, 0, 0);                  \
        }                                                                    \
        _Pragma("unroll")                                                    \
        for (int cbk = 0; cbk < COUTB; cbk++) {                              \
            unsigned int p = pack4_fp8(                                      \
                fmaxf(acc[cbk][0], 0.f), fmaxf(acc[cbk][1], 0.f),            \
                fmaxf(acc[cbk][2], 0.f), fmaxf(acc[cbk][3], 0.f));           \
            *(unsigned int*)(out + ((size_t)lrow * WW + xp_) * COUT +        \
                             cbk * 16 + sub * 4) = p;                        \
        }                                                                    \
    } while (0)

    bf16x8 bufA[NG], bufB[NG];
    LOADB(0, bufA);
#pragma unroll
    for (int tt = 0; tt < NT; tt += 2) {
        LOADB(tt + 1, bufB);
        COMPUTE(tt, bufA);
        if (tt + 2 < NT) LOADB(tt + 2, bufA);
        COMPUTE(tt + 1, bufB);
    }
#undef LOADB
#undef COMPUTE
}

// ---------------------------------------------------------------------------
// FINAL: fp8 input/weights, K=160. Fused res+attn+blend, wave-parallel
// epilogue (one transcendental per lane).
// ---------------------------------------------------------------------------
__global__ __launch_bounds__(256, 2) void final_kernel(
    const unsigned char* __restrict__ in, int in_y0, int in_rows,
    const unsigned char* __restrict__ wp, const float* __restrict__ ap,
    int out_y0, int out_rows,
    const float* __restrict__ xb, const float* __restrict__ stp,
    float* __restrict__ fout)
{
    constexpr int CI = 16, NG = 5;
    constexpr int SEGW = 192;
    constexpr int NT   = SEGW / 16;

    int l    = threadIdx.x & 63;
    int wv   = threadIdx.x >> 6;
    int lrow = blockIdx.y * 4 + wv;
    if (lrow >= out_rows) return;
    int y    = out_y0 + lrow;
    int x0   = blockIdx.x * SEGW;
    int mrow = l & 15;
    int sub  = l >> 4;

    f32x4 ainit = *(const f32x4*)(ap + (size_t)l * 4);

    u8x8 wf[NG];
#pragma unroll
    for (int g = 0; g < NG; g++)
        wf[g] = *(const u8x8*)(wp + ((size_t)g * 64 + l) * 8);

    float stv = clipf(stp[0], 0.02f, 0.2f);

    const unsigned char* baseg[NG];
    int dxg[NG];
    bool okg[NG];
#pragma unroll
    for (int g = 0; g < NG; g++) {
        int kl  = g * 32 + sub * 8;
        int tap = kl / CI;
        int cib = kl % CI;
        int dy = (tap < 9) ? tap / 3 - 1 : 0;
        int dx = (tap < 9) ? tap % 3 - 1 : 0;
        int yy = y + dy;
        okg[g] = (yy >= 0 && yy < HH);
        baseg[g] = in + ((long)(yy - in_y0) * WW + dx) * CI + cib;
        dxg[g] = dx;
    }

#define LOADB(t, buf)                                                        \
    do {                                                                     \
        int xp_ = x0 + (t) * 16 + mrow;                                      \
        _Pragma("unroll")                                                    \
        for (int g = 0; g < NG; g++) {                                       \
            int xx_ = xp_ + dxg[g];                                          \
            u8x8 v_ = {0, 0, 0, 0, 0, 0, 0, 0};                              \
            if (okg[g] && (unsigned)xx_ < (unsigned)WW)                      \
                v_ = *(const u8x8*)(baseg[g] + (size_t)xp_ * CI);            \
            buf[g] = v_;                                                     \
        }                                                                    \
    } while (0)

#define COMPUTE(t, buf)                                                      \
    do {                                                                     \
        int xp_ = x0 + (t) * 16 + mrow;                                      \
        float xbv_ = 0.f;                                                    \
        if (sub < 3)                                                         \
            xbv_ = xb[(size_t)sub * HWSZ + (size_t)y * WW + xp_];            \
        f32x4 acc = ainit;                                                   \
        _Pragma("unroll")                                                    \
        for (int g = 0; g < NG; g++)                                         \
            acc = __builtin_amdgcn_mfma_f32_16x16x32_fp8_fp8(                \
                *(const long long*)&wf[g], *(const long long*)&buf[g], acc,  \
                0, 0, 0);                                                    \
        float bc0_ = __shfl(acc[0], mrow);                                   \
        float bc1_ = __shfl(acc[1], mrow);                                   \
        float bc2_ = __shfl(acc[2], mrow);                                   \
        float bc3_ = __shfl(acc[3], mrow);                                   \
        float mv_ = (sub == 0) ? bc0_ : (sub == 1) ? bc1_                    \
                  : (sub == 2) ? bc2_ : bc3_;                                \
        float e_  = __expf((sub == 3) ? -mv_ : 2.f * mv_);                   \
        float tv_ = (sub == 3) ? 1.f / (1.f + e_)                            \
                               : 1.f - 2.f / (1.f + e_);                     \
        float atv_ = __shfl(tv_, 48 + mrow);                                 \
        if (sub < 3) {                                                       \
            size_t off_ = (size_t)sub * HWSZ + (size_t)y * WW + xp_;         \
            fout[off_] = clipf(xbv_ + stv * tv_ * atv_, 0.f, 1.f);           \
        }                                                                    \
    } while (0)

    u8x8 bufA[NG], bufB[NG];
    LOADB(0, bufA);
#pragma unroll
    for (int tt = 0; tt < NT; tt += 2) {
        LOADB(tt + 1, bufB);
        COMPUTE(tt, bufA);
        if (tt + 2 < NT) LOADB(tt + 2, bufA);
        COMPUTE(tt + 1, bufB);
    }
#undef LOADB
#undef COMPUTE
}

// ---------------------------------------------------------------------------
extern "C" void kernel_launch(void* const* d_in, const int* in_sizes, int n_in,
                              void* d_out, int out_size, void* d_ws, size_t ws_size,
                              hipStream_t stream)
{
    const float* x   = (const float*)d_in[0];
    const float* lut = (const float*)d_in[1];
    const float* cm  = (const float*)d_in[2];
    const float* cb  = (const float*)d_in[3];
    const float* sh  = (const float*)d_in[4];
    const float* mi  = (const float*)d_in[5];
    const float* hi  = (const float*)d_in[6];
    const float* co  = (const float*)d_in[7];
    const float* sa  = (const float*)d_in[8];
    const float* wa  = (const float*)d_in[9];
    const float* lb  = (const float*)d_in[10];
    const float* st  = (const float*)d_in[11];
    const float* w1  = (const float*)d_in[12];
    const float* g1  = (const float*)d_in[13];
    const float* b1  = (const float*)d_in[14];
    const float* m1  = (const float*)d_in[15];
    const float* v1  = (const float*)d_in[16];
    const float* w2  = (const float*)d_in[17];
    const float* g2  = (const float*)d_in[18];
    const float* b2  = (const float*)d_in[19];
    const float* m2  = (const float*)d_in[20];
    const float* v2  = (const float*)d_in[21];
    const float* w3  = (const float*)d_in[22];
    const float* g3  = (const float*)d_in[23];
    const float* b3  = (const float*)d_in[24];
    const float* m3  = (const float*)d_in[25];
    const float* v3  = (const float*)d_in[26];
    const float* rw  = (const float*)d_in[27];
    const float* rb  = (const float*)d_in[28];
    const float* aw  = (const float*)d_in[29];
    const float* ab  = (const float*)d_in[30];

    // Workspace: xb f32 24.9MB | xin bf16 33.2MB | f1 fp8 33.4MB | f2 fp8 33.4MB
    char* ws = (char*)d_ws;
    const size_t XB_BYTES  = (size_t)3 * HWSZ * sizeof(float);
    const size_t XIN_BYTES = (size_t)8 * HWSZ * sizeof(__hip_bfloat16);
    const size_t F8_BYTES  = (size_t)32 * 543 * WW;   // fp8: 1 B/elem
    float* xb = (float*)ws;
    __hip_bfloat16* xin = (__hip_bfloat16*)(ws + XB_BYTES);
    unsigned char* f1 = (unsigned char*)(ws + XB_BYTES + XIN_BYTES);
    unsigned char* f2 = (unsigned char*)(ws + XB_BYTES + XIN_BYTES + F8_BYTES);
    unsigned char* f3 = f1;   // f1 dead once conv2 of this half is done

    char* pk = ws + XB_BYTES + XIN_BYTES + 2 * F8_BYTES;
    unsigned char* wp1 = (unsigned char*)(pk);           // bf16: 6144 B
    float* ap1 = (float*)(pk + 6144);                    // 2048 B
    unsigned char* wp2 = (unsigned char*)(pk + 8192);    // fp8: 9216 B
    float* ap2 = (float*)(pk + 17408);                   // 2048 B
    unsigned char* wp3 = (unsigned char*)(pk + 19456);   // fp8: 4608 B
    float* ap3 = (float*)(pk + 24064);                   // 1024 B
    unsigned char* wp4 = (unsigned char*)(pk + 25088);   // fp8: 2560 B
    float* ap4 = (float*)(pk + 27648);                   // 1024 B

    pack_weights<8, 6, 2, 32, 3, false, false><<<2, 256, 0, stream>>>(
        w1, nullptr, g1, b1, m1, v1, wp1, ap1);
    pack_weights<32, 32, 2, 32, 9, false, true><<<5, 256, 0, stream>>>(
        w2, nullptr, g2, b2, m2, v2, wp2, ap2);
    pack_weights<32, 32, 1, 16, 9, false, true><<<3, 256, 0, stream>>>(
        w3, nullptr, g3, b3, m3, v3, wp3, ap3);
    pack_weights<16, 16, 1, 4, 5, true, true><<<2, 256, 0, stream>>>(
        rw, aw, rb, rb, ab, ab, wp4, ap4);

    {
        int grid = (HWSZ + 255) / 256;
        grade_kernel<<<grid, 256, 0, stream>>>(x, lut, cm, cb, sh, mi, hi, co,
                                               sa, wa, lb, xb, xin);
    }

    for (int h = 0; h < 2; h++) {
        int r0 = (h == 0) ? 0 : HH / 2;
        int r1 = (h == 0) ? HH / 2 : HH;

        int f1_y0 = max(r0 - 3, 0), f1_y1 = min(r1 + 3, HH);
        int f2_y0 = max(r0 - 2, 0), f2_y1 = min(r1 + 2, HH);
        int f3_y0 = max(r0 - 1, 0), f3_y1 = min(r1 + 1, HH);
        int f1_rows = f1_y1 - f1_y0;
        int f2_rows = f2_y1 - f2_y0;
        int f3_rows = f3_y1 - f3_y0;
        int out_rows = r1 - r0;

        dim3 blk(256);
        dim3 gr1(10, (f1_rows + 3) / 4);
        dim3 gr2s(60, (f2_rows + 7) / 8);   // NCB=2: XT=2, 32 px/block
        dim3 gr3s(30, (f3_rows + 7) / 8);   // NCB=1: XT=4, 64 px/block
        dim3 gr4(10, (out_rows + 3) / 4);

        // conv1: 6(->8 padded) -> 32, bf16 MFMA, fp8 output
        conv1_kernel<<<gr1, blk, 0, stream>>>(
            xin, wp1, ap1, f1, f1_y0, f1_rows);
        // conv2: 32 -> 32, fp8 (2-row dual-chain slide, channel-split waves)
        conv_fp8_slide<2><<<gr2s, blk, 0, stream>>>(
            f1, f1_y0, f1_rows, wp2, ap2, f2, f2_y0, f2_rows);
        // conv3: 32 -> 16, fp8 (2-row dual-chain slide)
        conv_fp8_slide<1><<<gr3s, blk, 0, stream>>>(
            f2, f2_y0, f2_rows, wp3, ap3, f3, f3_y0, f3_rows);
        // final: 16 -> 4 (res0-2 + attn), fp8 MFMA, fused blend + wave-parallel
        // epilogue
        final_kernel<<<gr4, blk, 0, stream>>>(
            f3, f3_y0, f3_rows, wp4, ap4, r0, out_rows,
            xb, st, (float*)d_out);
    }
}

// Round 14
// 320.326 us; speedup vs baseline: 1.1572x; 1.0683x over previous
//
#include <hip/hip_runtime.h>
#include <hip/hip_bf16.h>

#define HH 1080
#define WW 1920
#define HWSZ (HH * WW)

typedef __attribute__((ext_vector_type(8))) short bf16x8;
typedef __attribute__((ext_vector_type(4))) float f32x4;
typedef __attribute__((ext_vector_type(8))) unsigned char u8x8;

__device__ __forceinline__ float clipf(float x, float lo, float hi) {
    return fminf(fmaxf(x, lo), hi);
}
__device__ __forceinline__ short f2bf(float f) {
    __hip_bfloat16 h = __float2bfloat16(f);
    return *(short*)&h;
}
// f32 -> OCP e4m3 fp8 via native cvt (no hip_fp8.h dependency; verified R13)
__device__ __forceinline__ unsigned int pack4_fp8(float a, float b, float c, float d) {
    int p = __builtin_amdgcn_cvt_pk_fp8_f32(a, b, 0, false);
    p = __builtin_amdgcn_cvt_pk_fp8_f32(c, d, p, true);
    return (unsigned int)p;
}
__device__ __forceinline__ float fpow(float a, float e) {
    return __expf(__logf(a) * e);   // a >= 1e-7 guaranteed by callers
}

// ---------------------------------------------------------------------------
// Kernel 1: classical grade + 3D LUT + blend.
// Writes: xb (planar bf16) and xin (NHWC fp8 8ch: x0..2, xb0..2, 0, 0).
// ---------------------------------------------------------------------------
__global__ __launch_bounds__(256) void grade_kernel(
    const float* __restrict__ x, const float* __restrict__ lut,
    const float* __restrict__ cm, const float* __restrict__ cbp,
    const float* __restrict__ shp, const float* __restrict__ mip,
    const float* __restrict__ hip_, const float* __restrict__ cop,
    const float* __restrict__ satp, const float* __restrict__ wap,
    const float* __restrict__ lbp,
    __hip_bfloat16* __restrict__ xb, unsigned char* __restrict__ xin)
{
    int i = blockIdx.x * blockDim.x + threadIdx.x;
    if (i >= HWSZ) return;

    float in0 = x[i], in1 = x[HWSZ + i], in2 = x[2 * HWSZ + i];

    float M00 = clipf(cm[0], 0.9f, 1.1f), M01 = clipf(cm[1], 0.9f, 1.1f), M02 = clipf(cm[2], 0.9f, 1.1f);
    float M10 = clipf(cm[3], 0.9f, 1.1f), M11 = clipf(cm[4], 0.9f, 1.1f), M12 = clipf(cm[5], 0.9f, 1.1f);
    float M20 = clipf(cm[6], 0.9f, 1.1f), M21 = clipf(cm[7], 0.9f, 1.1f), M22 = clipf(cm[8], 0.9f, 1.1f);
    float bi0 = clipf(cbp[0], -0.02f, 0.02f);
    float bi1 = clipf(cbp[1], -0.02f, 0.02f);
    float bi2 = clipf(cbp[2], -0.02f, 0.02f);

    float sh  = clipf(shp[0], -0.02f, 0.05f);
    float mi  = clipf(mip[0], 0.95f, 1.05f);
    float hi  = clipf(hip_[0], 0.95f, 1.05f);
    float co  = clipf(cop[0], 0.98f, 1.05f);
    float sat = clipf(satp[0], 0.95f, 1.3f);
    float wa  = clipf(wap[0], -0.02f, 0.05f);
    float lb  = clipf(lbp[0], 0.7f, 0.9f);

    float xc[3];
    xc[0] = M00 * in0 + M01 * in1 + M02 * in2 + bi0;
    xc[1] = M10 * in0 + M11 * in1 + M12 * in2 + bi1;
    xc[2] = M20 * in0 + M21 * in1 + M22 * in2 + bi2;

    float inv_mi = 1.0f / mi, inv_co = 1.0f / co;
    float xg[3];
#pragma unroll
    for (int c = 0; c < 3; c++) {
        float v = xc[c];
        float sm = clipf(1.f - v, 0.f, 1.f);
        sm = sm * sm * sm;
        float xs = v + sh * sm * (1.f - v) * 0.5f;
        float xm = fpow(clipf(xs, 1e-7f, 1.f), inv_mi);
        float hm = clipf(xm, 0.f, 1.f);
        hm = hm * hm * hm;
        float x2 = clipf(xm * (1.f - hm * (1.f - hi) * 0.5f), 0.f, 1.f);
        xg[c] = fpow(clipf(x2, 1e-7f, 1.f), inv_co);
    }

    float luma = 0.299f * xg[0] + 0.587f * xg[1] + 0.114f * xg[2];
    float s0 = luma + sat * (xg[0] - luma);
    float s1 = luma + sat * (xg[1] - luma);
    float s2 = luma + sat * (xg[2] - luma);

    float pr = clipf(s0 * (1.f + wa), 0.f, 1.f);
    float pg = clipf(s1 * (1.f + wa * 0.3f), 0.f, 1.f);
    float pb = clipf(s2 * (1.f - wa * 0.5f), 0.f, 1.f);

    float cr = pr * 32.f, cg = pg * 32.f, cb2 = pb * 32.f;
    float fr = floorf(cr), fgq = floorf(cg), fb = floorf(cb2);
    float fx = cr - fr, fy = cg - fgq, fz = cb2 - fb;
    int x0 = min(max((int)fr, 0), 31);
    int y0 = min(max((int)fgq, 0), 31);
    int z0 = min(max((int)fb, 0), 31);

    const float* base = lut + ((x0 * 33 + y0) * 33 + z0) * 3;
    float pcl[3] = {pr, pg, pb};
    float bl[3];
#pragma unroll
    for (int ch = 0; ch < 3; ch++) {
        float c000 = base[ch];
        float c001 = base[3 + ch];
        float c010 = base[99 + ch];
        float c011 = base[102 + ch];
        float c100 = base[3267 + ch];
        float c101 = base[3270 + ch];
        float c110 = base[3366 + ch];
        float c111 = base[3369 + ch];
        float c00 = c000 * (1.f - fx) + c100 * fx;
        float c01 = c001 * (1.f - fx) + c101 * fx;
        float c10 = c010 * (1.f - fx) + c110 * fx;
        float c11 = c011 * (1.f - fx) + c111 * fx;
        float c0 = c00 * (1.f - fy) + c10 * fy;
        float c1 = c01 * (1.f - fy) + c11 * fy;
        float lv = c0 * (1.f - fz) + c1 * fz;
        bl[ch] = lb * lv + (1.f - lb) * pcl[ch];
        xb[(size_t)ch * HWSZ + i] = __float2bfloat16(bl[ch]);
    }

    unsigned int lo = pack4_fp8(in0, in1, in2, bl[0]);
    unsigned int hi2 = pack4_fp8(bl[1], bl[2], 0.f, 0.f);
    unsigned int p[2] = {lo, hi2};
    *(u8x8*)(xin + (size_t)i * 8) = *(u8x8*)p;
}

// ---------------------------------------------------------------------------
// Pack kernel: fold BN into weights, emit per-lane fp8 MFMA A-fragments +
// acc-init. wp: frag (cb,g), lane l -> wp[((cb*NG+g)*64 + l)*8 + j]  (fp8)
// ap: (cb, lane l) -> ap[(cb*64 + l)*4 + r]  (f32)
// ---------------------------------------------------------------------------
template <int CI, int CIR, int COUTB, int COUTR, int NG, bool FINAL>
__global__ __launch_bounds__(256) void pack_weights(
    const float* __restrict__ w, const float* __restrict__ w2,
    const float* __restrict__ bg, const float* __restrict__ bb,
    const float* __restrict__ bm, const float* __restrict__ bv,
    unsigned char* __restrict__ wp, float* __restrict__ ap)
{
    int t = blockIdx.x * blockDim.x + threadIdx.x;
    constexpr int NFRAG = COUTB * NG * 64;
    if (t < NFRAG) {
        int l    = t & 63;
        int frag = t >> 6;
        int g    = frag % NG;
        int cbk  = frag / NG;
        int mrow = l & 15;
        int sub  = l >> 4;
        int cout = cbk * 16 + mrow;
        float scl = 1.f;
        if (!FINAL)
            scl = (cout < COUTR) ? bg[cout] * rsqrtf(bv[cout] + 1e-5f) : 0.f;
        float vals[8];
#pragma unroll
        for (int j = 0; j < 8; j++) {
            int k   = g * 32 + sub * 8 + j;
            int tap = k / CI;
            int ci  = k % CI;
            float val = 0.f;
            if (tap < 9 && ci < CIR && cout < COUTR) {
                if (FINAL)
                    val = (cout < 3) ? w[(cout * CIR + ci) * 9 + tap]
                                     : w2[ci * 9 + tap];
                else
                    val = w[(cout * CIR + ci) * 9 + tap] * scl;
            }
            vals[j] = val;
        }
        unsigned int lo = pack4_fp8(vals[0], vals[1], vals[2], vals[3]);
        unsigned int hi = pack4_fp8(vals[4], vals[5], vals[6], vals[7]);
        unsigned int p[2] = {lo, hi};
        *(u8x8*)(wp + (size_t)t * 8) = *(u8x8*)p;
    } else if (t < NFRAG + COUTB * 64) {
        int u   = t - NFRAG;
        int l   = u & 63;
        int cbk = u >> 6;
        int sub = l >> 4;
        f32x4 a;
#pragma unroll
        for (int r = 0; r < 4; r++) {
            int c = cbk * 16 + sub * 4 + r;
            float v = 0.f;
            if (FINAL) {
                v = (c < 3) ? bb[c] : (c == 3 ? bm[0] : 0.f);
            } else if (c < COUTR) {
                float s = bg[c] * rsqrtf(bv[c] + 1e-5f);
                v = bb[c] - bm[c] * s;
            }
            a[r] = v;
        }
        *(f32x4*)(ap + (size_t)u * 4) = a;
    }
}

// ---------------------------------------------------------------------------
// Sliding-window fp8 MFMA conv, CI=32 (conv2/conv3), 2 rows per step.
// 4-row tap window, two interleaved MFMA chains, loads into dead slots.
// ---------------------------------------------------------------------------
template <int NCB>
__global__ __launch_bounds__(256, 4) void conv_fp8_slide(
    const unsigned char* __restrict__ in,
    const unsigned char* __restrict__ wp, const float* __restrict__ ap,
    unsigned char* __restrict__ out)
{
    constexpr int COUT = NCB * 16;     // output channel stride (bytes)
    constexpr int XT   = 4 / NCB;      // column tiles per block
    constexpr int RPW  = 8;

    int l    = threadIdx.x & 63;
    int wv   = threadIdx.x >> 6;
    int mrow = l & 15;
    int sub  = l >> 4;
    int xt   = wv % XT;
    int chb  = wv / XT;

    int xp = (blockIdx.x * XT + xt) * 16 + mrow;
    int r0 = blockIdx.y * RPW;
    if (r0 >= HH) return;
    int y0 = r0;

    f32x4 ainit = *(const f32x4*)(ap + ((size_t)chb * 64 + l) * 4);

    u8x8 wf[9];
#pragma unroll
    for (int g = 0; g < 9; g++)
        wf[g] = *(const u8x8*)(wp + ((size_t)(chb * 9 + g) * 64 + l) * 8);

    bool xl = xp > 0, xh = xp < WW - 1;
    const unsigned char* inb = in + sub * 8;

#define ROWLOAD(yy, d0, d1, d2)                                              \
    do {                                                                     \
        int ybuf_ = min(max((yy), 0), HH - 1);                               \
        const unsigned char* rb_ = inb + (size_t)ybuf_ * (WW * 32);          \
        bool yok_ = (unsigned)(yy) < (unsigned)HH;                           \
        u8x8 z_ = {0, 0, 0, 0, 0, 0, 0, 0};                                  \
        d0 = (yok_ && xl) ? *(const u8x8*)(rb_ + (size_t)(xp - 1) * 32) : z_; \
        d1 = yok_         ? *(const u8x8*)(rb_ + (size_t)xp * 32)       : z_; \
        d2 = (yok_ && xh) ? *(const u8x8*)(rb_ + (size_t)(xp + 1) * 32) : z_; \
    } while (0)

#define MFMA(w_, t_, acc_)                                                   \
    acc_ = __builtin_amdgcn_mfma_f32_16x16x32_fp8_fp8(                       \
        *(const long long*)&(w_), *(const long long*)&(t_), acc_, 0, 0, 0)

    u8x8 a0, a1, a2, b0, b1, b2, c0, c1, c2, d0, d1, d2;
    ROWLOAD(y0 - 1, a0, a1, a2);
    ROWLOAD(y0,     b0, b1, b2);
    ROWLOAD(y0 + 1, c0, c1, c2);
    ROWLOAD(y0 + 2, d0, d1, d2);

#pragma unroll
    for (int s = 0; s < RPW / 2; s++) {
        int r = r0 + 2 * s;
        f32x4 accA = ainit;   // row r     (taps a,b,c)
        f32x4 accB = ainit;   // row r + 1 (taps b,c,d)

        MFMA(wf[0], a0, accA);  MFMA(wf[0], b0, accB);
        MFMA(wf[1], a1, accA);  MFMA(wf[1], b1, accB);
        MFMA(wf[2], a2, accA);  MFMA(wf[2], b2, accB);
        if (s < RPW / 2 - 1) ROWLOAD(y0 + 2 * s + 3, a0, a1, a2);
        MFMA(wf[3], b0, accA);  MFMA(wf[3], c0, accB);
        MFMA(wf[4], b1, accA);  MFMA(wf[4], c1, accB);
        MFMA(wf[5], b2, accA);  MFMA(wf[5], c2, accB);
        if (s < RPW / 2 - 1) ROWLOAD(y0 + 2 * s + 4, b0, b1, b2);
        MFMA(wf[6], c0, accA);  MFMA(wf[6], d0, accB);
        MFMA(wf[7], c1, accA);  MFMA(wf[7], d1, accB);
        MFMA(wf[8], c2, accA);  MFMA(wf[8], d2, accB);

        if (r < HH) {
            unsigned int p = pack4_fp8(fmaxf(accA[0], 0.f), fmaxf(accA[1], 0.f),
                                       fmaxf(accA[2], 0.f), fmaxf(accA[3], 0.f));
            *(unsigned int*)(out + ((size_t)r * WW + xp) * COUT + chb * 16 + sub * 4) = p;
        }
        if (r + 1 < HH) {
            unsigned int p = pack4_fp8(fmaxf(accB[0], 0.f), fmaxf(accB[1], 0.f),
                                       fmaxf(accB[2], 0.f), fmaxf(accB[3], 0.f));
            *(unsigned int*)(out + ((size_t)(r + 1) * WW + xp) * COUT + chb * 16 + sub * 4) = p;
        }

        {
            u8x8 t;
            t = a0; a0 = c0; c0 = t;
            t = a1; a1 = c1; c1 = t;
            t = a2; a2 = c2; c2 = t;
            t = b0; b0 = d0; d0 = t;
            t = b1; b1 = d1; d1 = t;
            t = b2; b2 = d2; d2 = t;
        }
    }
#undef MFMA
#undef ROWLOAD
}

// ---------------------------------------------------------------------------
// Tile-pipelined fp8 MFMA conv (conv1 CI=8 and FINAL CI=16), full image.
// FINAL epilogue wave-parallel (one transcendental per lane), reads bf16 xb.
// ---------------------------------------------------------------------------
template <int CI, int COUTB, int NG, bool FINAL>
__global__ __launch_bounds__(256, 2) void conv_fp8_tile(
    const unsigned char* __restrict__ in,
    const unsigned char* __restrict__ wp, const float* __restrict__ ap,
    unsigned char* __restrict__ out,
    const __hip_bfloat16* __restrict__ xb, const float* __restrict__ stp,
    float* __restrict__ fout)
{
    constexpr int COUT = COUTB * 16;
    constexpr int SEGW = 192;
    constexpr int NT   = SEGW / 16;

    int l    = threadIdx.x & 63;
    int wv   = threadIdx.x >> 6;
    int y    = blockIdx.y * 4 + wv;
    if (y >= HH) return;
    int x0   = blockIdx.x * SEGW;
    int mrow = l & 15;
    int sub  = l >> 4;

    f32x4 ainit[COUTB];
#pragma unroll
    for (int cbk = 0; cbk < COUTB; cbk++)
        ainit[cbk] = *(const f32x4*)(ap + ((size_t)cbk * 64 + l) * 4);

    u8x8 wf[COUTB][NG];
#pragma unroll
    for (int cbk = 0; cbk < COUTB; cbk++)
#pragma unroll
        for (int g = 0; g < NG; g++)
            wf[cbk][g] = *(const u8x8*)(wp + ((size_t)(cbk * NG + g) * 64 + l) * 8);

    float stv = 0.f;
    if (FINAL) stv = clipf(stp[0], 0.02f, 0.2f);

    const unsigned char* baseg[NG];
    int dxg[NG];
    bool okg[NG];
#pragma unroll
    for (int g = 0; g < NG; g++) {
        int kl  = g * 32 + sub * 8;
        int tap = kl / CI;
        int cib = kl % CI;
        int dy = (tap < 9) ? tap / 3 - 1 : 0;
        int dx = (tap < 9) ? tap % 3 - 1 : 0;
        int yy = y + dy;
        okg[g] = (yy >= 0 && yy < HH);
        baseg[g] = in + ((long)yy * WW + dx) * CI + cib;
        dxg[g] = dx;
    }

#define LOADB(t, buf)                                                        \
    do {                                                                     \
        int xp_ = x0 + (t) * 16 + mrow;                                      \
        _Pragma("unroll")                                                    \
        for (int g = 0; g < NG; g++) {                                       \
            int xx_ = xp_ + dxg[g];                                          \
            u8x8 v_ = {0, 0, 0, 0, 0, 0, 0, 0};                              \
            if (okg[g] && (unsigned)xx_ < (unsigned)WW)                      \
                v_ = *(const u8x8*)(baseg[g] + (size_t)xp_ * CI);            \
            buf[g] = v_;                                                     \
        }                                                                    \
    } while (0)

#define COMPUTE(t, buf)                                                      \
    do {                                                                     \
        int xp_ = x0 + (t) * 16 + mrow;                                      \
        float xbv_ = 0.f;                                                    \
        if (FINAL && sub < 3)                                                \
            xbv_ = __bfloat162float(                                         \
                xb[(size_t)sub * HWSZ + (size_t)y * WW + xp_]);              \
        f32x4 acc[COUTB];                                                    \
        _Pragma("unroll")                                                    \
        for (int cbk = 0; cbk < COUTB; cbk++) acc[cbk] = ainit[cbk];         \
        _Pragma("unroll")                                                    \
        for (int g = 0; g < NG; g++) {                                       \
            _Pragma("unroll")                                                \
            for (int cbk = 0; cbk < COUTB; cbk++)                            \
                acc[cbk] = __builtin_amdgcn_mfma_f32_16x16x32_fp8_fp8(       \
                    *(const long long*)&wf[cbk][g],                          \
                    *(const long long*)&buf[g], acc[cbk], 0, 0, 0);          \
        }                                                                    \
        if constexpr (!FINAL) {                                              \
            _Pragma("unroll")                                                \
            for (int cbk = 0; cbk < COUTB; cbk++) {                          \
                unsigned int p = pack4_fp8(                                  \
                    fmaxf(acc[cbk][0], 0.f), fmaxf(acc[cbk][1], 0.f),        \
                    fmaxf(acc[cbk][2], 0.f), fmaxf(acc[cbk][3], 0.f));       \
                *(unsigned int*)(out + ((size_t)y * WW + xp_) * COUT +       \
                                 cbk * 16 + sub * 4) = p;                    \
            }                                                                \
        } else {                                                             \
            float bc0_ = __shfl(acc[0][0], mrow);                            \
            float bc1_ = __shfl(acc[0][1], mrow);                            \
            float bc2_ = __shfl(acc[0][2], mrow);                            \
            float bc3_ = __shfl(acc[0][3], mrow);                            \
            float mv_ = (sub == 0) ? bc0_ : (sub == 1) ? bc1_                \
                      : (sub == 2) ? bc2_ : bc3_;                            \
            float e_  = __expf((sub == 3) ? -mv_ : 2.f * mv_);               \
            float tv_ = (sub == 3) ? 1.f / (1.f + e_)                        \
                                   : 1.f - 2.f / (1.f + e_);                 \
            float atv_ = __shfl(tv_, 48 + mrow);                             \
            if (sub < 3) {                                                   \
                size_t off_ = (size_t)sub * HWSZ + (size_t)y * WW + xp_;     \
                fout[off_] = clipf(xbv_ + stv * tv_ * atv_, 0.f, 1.f);       \
            }                                                                \
        }                                                                    \
    } while (0)

    u8x8 bufA[NG], bufB[NG];
    LOADB(0, bufA);
#pragma unroll
    for (int tt = 0; tt < NT; tt += 2) {
        LOADB(tt + 1, bufB);
        COMPUTE(tt, bufA);
        if (tt + 2 < NT) LOADB(tt + 2, bufA);
        COMPUTE(tt + 1, bufB);
    }
#undef LOADB
#undef COMPUTE
}

// ---------------------------------------------------------------------------
extern "C" void kernel_launch(void* const* d_in, const int* in_sizes, int n_in,
                              void* d_out, int out_size, void* d_ws, size_t ws_size,
                              hipStream_t stream)
{
    const float* x   = (const float*)d_in[0];
    const float* lut = (const float*)d_in[1];
    const float* cm  = (const float*)d_in[2];
    const float* cb  = (const float*)d_in[3];
    const float* sh  = (const float*)d_in[4];
    const float* mi  = (const float*)d_in[5];
    const float* hi  = (const float*)d_in[6];
    const float* co  = (const float*)d_in[7];
    const float* sa  = (const float*)d_in[8];
    const float* wa  = (const float*)d_in[9];
    const float* lb  = (const float*)d_in[10];
    const float* st  = (const float*)d_in[11];
    const float* w1  = (const float*)d_in[12];
    const float* g1  = (const float*)d_in[13];
    const float* b1  = (const float*)d_in[14];
    const float* m1  = (const float*)d_in[15];
    const float* v1  = (const float*)d_in[16];
    const float* w2  = (const float*)d_in[17];
    const float* g2  = (const float*)d_in[18];
    const float* b2  = (const float*)d_in[19];
    const float* m2  = (const float*)d_in[20];
    const float* v2  = (const float*)d_in[21];
    const float* w3  = (const float*)d_in[22];
    const float* g3  = (const float*)d_in[23];
    const float* b3  = (const float*)d_in[24];
    const float* m3  = (const float*)d_in[25];
    const float* v3  = (const float*)d_in[26];
    const float* rw  = (const float*)d_in[27];
    const float* rb  = (const float*)d_in[28];
    const float* aw  = (const float*)d_in[29];
    const float* ab  = (const float*)d_in[30];

    // Workspace (single-pass, ~162 MB):
    //   xb  : planar bf16, 3*HWSZ      = 12.4 MB
    //   xin : NHWC fp8, 8ch            = 16.6 MB
    //   f1  : NHWC fp8, 32ch full      = 66.4 MB   (f3 aliases f1)
    //   f2  : NHWC fp8, 32ch full      = 66.4 MB
    char* ws = (char*)d_ws;
    const size_t XB_BYTES  = (size_t)3 * HWSZ * sizeof(__hip_bfloat16);
    const size_t XIN_BYTES = (size_t)8 * HWSZ;
    const size_t F8_BYTES  = (size_t)32 * HWSZ;
    __hip_bfloat16* xb = (__hip_bfloat16*)ws;
    unsigned char* xin = (unsigned char*)(ws + XB_BYTES);
    unsigned char* f1  = (unsigned char*)(ws + XB_BYTES + XIN_BYTES);
    unsigned char* f2  = (unsigned char*)(ws + XB_BYTES + XIN_BYTES + F8_BYTES);
    unsigned char* f3  = f1;   // f1 dead once conv2 done

    char* pk = ws + XB_BYTES + XIN_BYTES + 2 * F8_BYTES;
    unsigned char* wp1 = (unsigned char*)(pk);           // fp8: 2*3*64*8 = 3072 B
    float* ap1 = (float*)(pk + 3072);                    // 2048 B
    unsigned char* wp2 = (unsigned char*)(pk + 5120);    // fp8: 9216 B
    float* ap2 = (float*)(pk + 14336);                   // 2048 B
    unsigned char* wp3 = (unsigned char*)(pk + 16384);   // fp8: 4608 B
    float* ap3 = (float*)(pk + 20992);                   // 1024 B
    unsigned char* wp4 = (unsigned char*)(pk + 22016);   // fp8: 2560 B
    float* ap4 = (float*)(pk + 24576);                   // 1024 B

    pack_weights<8, 6, 2, 32, 3, false><<<2, 256, 0, stream>>>(
        w1, nullptr, g1, b1, m1, v1, wp1, ap1);
    pack_weights<32, 32, 2, 32, 9, false><<<5, 256, 0, stream>>>(
        w2, nullptr, g2, b2, m2, v2, wp2, ap2);
    pack_weights<32, 32, 1, 16, 9, false><<<3, 256, 0, stream>>>(
        w3, nullptr, g3, b3, m3, v3, wp3, ap3);
    pack_weights<16, 16, 1, 4, 5, true><<<2, 256, 0, stream>>>(
        rw, aw, rb, rb, ab, ab, wp4, ap4);

    {
        int grid = (HWSZ + 255) / 256;
        grade_kernel<<<grid, 256, 0, stream>>>(x, lut, cm, cb, sh, mi, hi, co,
                                               sa, wa, lb, xb, xin);
    }

    dim3 blk(256);
    dim3 gr1(10, (HH + 3) / 4);        // conv1/final: 4 rows per block
    dim3 gr2s(60, (HH + 7) / 8);       // conv2 slide: NCB=2, XT=2
    dim3 gr3s(30, (HH + 7) / 8);       // conv3 slide: NCB=1, XT=4

    // conv1: 6(->8 padded) -> 32, fp8 MFMA, full image
    conv_fp8_tile<8, 2, 3, false><<<gr1, blk, 0, stream>>>(
        xin, wp1, ap1, f1, nullptr, nullptr, nullptr);
    // conv2: 32 -> 32, fp8 slide
    conv_fp8_slide<2><<<gr2s, blk, 0, stream>>>(f1, wp2, ap2, f2);
    // conv3: 32 -> 16, fp8 slide
    conv_fp8_slide<1><<<gr3s, blk, 0, stream>>>(f2, wp3, ap3, f3);
    // final: 16 -> 4 (res0-2 + attn), fused blend + wave-parallel epilogue
    conv_fp8_tile<16, 1, 5, true><<<gr1, blk, 0, stream>>>(
        f3, wp4, ap4, nullptr, xb, st, (float*)d_out);
}